// Round 21
// baseline (108.406 us; speedup 1.0000x reference)
//
#include <hip/hip_runtime.h>
#include <hip/hip_bf16.h>

typedef __attribute__((ext_vector_type(4))) float f32x4;
typedef __attribute__((ext_vector_type(8))) short s16x8;
typedef __attribute__((ext_vector_type(4))) short s16x4;

#define MFMA16(a, b, c) __builtin_amdgcn_mfma_f32_16x16x32_bf16(a, b, c, 0, 0, 0)

#define QSCALE 0.17677669529663687f

// integer RNE -- k_prep only
__device__ __forceinline__ unsigned short f2bf(float f) {
  union { float f; unsigned u; } v; v.f = f;
  unsigned u = v.u;
  u += 0x7fff + ((u >> 16) & 1);   // RNE
  return (unsigned short)(u >> 16);
}
// compiler-native RNE conversion (hot path)
__device__ __forceinline__ unsigned short nf2bf(float f) {
  __hip_bfloat16 h = __float2bfloat16(f);
  return *reinterpret_cast<unsigned short*>(&h);
}
__device__ __forceinline__ unsigned pk2(float a, float b) {
  union { unsigned u; unsigned short s[2]; } t;
  t.s[0] = nf2bf(a);
  t.s[1] = nf2bf(b);
  return t.u;
}

// ---------------------------------------------------------------------------
// Prepass (unchanged from R20).  W2F/W3F fragment order; BIASA MFMA-C layout.
// ---------------------------------------------------------------------------
__global__ void k_prep(const float* __restrict__ QW, const float* __restrict__ OW,
                       const float* __restrict__ RPE,
                       unsigned short* __restrict__ W2F, unsigned short* __restrict__ W3F,
                       float* __restrict__ BIASA) {
  const int b = blockIdx.x, t = threadIdx.x;
  if (b < 24) {                       // qkv_w -> fragment order
    const int e = (b * 256 + t) * 8;
    const int bi = e >> 9;            // (s*4+kc)*8 + jg
    const int l = (e >> 3) & 63;
    const int s = bi >> 5;
    const int kc = (bi >> 3) & 3;
    const int jg = bi & 7;
    const int li = l & 15, hi = l >> 4;
    const int c2 = ((jg >> 2) << 6) + li * 4 + (jg & 3);
    const int k0 = kc * 32 + hi * 8;
    const float sf = (s == 0) ? QSCALE : 1.0f;
    const float* src = QW + (size_t)(c2 * 3 + s) * 128 + k0;
#pragma unroll
    for (int q = 0; q < 8; ++q) W2F[e + q] = f2bf(src[q] * sf);
  } else if (b < 32) {                // out_w -> fragment order (W3F)
    const int e = ((b - 24) * 256 + t) * 8;
    const int bi = e >> 9;            // kc*8 + jg
    const int l = (e >> 3) & 63;
    const int kc = bi >> 3;
    const int jg = bi & 7;
    const int li = l & 15, hi = l >> 4;
    const int c2 = ((jg >> 2) << 6) + li * 4 + (jg & 3);
    const int k0 = kc * 32 + hi * 8;
    const float* src = OW + (size_t)c2 * 128 + k0;
#pragma unroll
    for (int q = 0; q < 8; ++q) W3F[e + q] = f2bf(src[q]);
  } else {                            // bias tables in acc-fragment layout
    const int cl = b - 32;
    const int rm = cl >> 1, cm = cl & 1;
    for (int w = 0; w < 16; ++w) {
      const int idx = w * 256 + t;       // ((i*4+j)*64 + lane)*4 + rr
      const int rr = idx & 3;
      const int lane = (idx >> 2) & 63;
      const int ij = idx >> 8;
      const int q = (ij >> 2) * 16 + ((lane >> 4) & 3) * 4 + rr;
      const int k = (lane & 15) * 4 + (ij & 3);       // permuted-k mapping
      float v;
      if (q >= 49 || k >= 49) v = -1.0e30f;
      else {
        const int xq = q / 7, yq = q - xq * 7;
        const int xk = k / 7, yk = k - xk * 7;
        v = RPE[(xk - xq + 6) * 13 + (yk - yq + 6)];
        if (rm && ((xq >= 4) != (xk >= 4))) v = -1.0e30f;
        if (cm && (((yq == 4) && (yk < 4)) || ((yq < 4) && (yk >= 4)))) v = -1.0e30f;
      }
      BIASA[cl * 4096 + idx] = v;
    }
  }
}

// ---------------------------------------------------------------------------
// FULLY FUSED (R20 structure) with LDS trimmed to 39424 B -> 4 blocks/CU:
// A-fragments direct global->VGPR gather (R12 pattern, == staged perf); the
// O tile moves into the dead P region (Q space) behind a new barrier.
// LDS: Q @0 (12544), K @12544, V @25088 (56 rows, 49..55 zeroed) = 39424 B.
// P = per-wave 6272 B at wid*6272 (spans Q+K, after barrier 2).
// O = [49][128ch] tile at 0 (spans waves 0-1 P; written after barrier 3).
// ---------------------------------------------------------------------------
#define Q_OFF 0
#define K_OFF 12544
#define V_OFF 25088
#define PW_STR 6272

__global__ __launch_bounds__(256, 4)
void k_fused(const float* __restrict__ X, const unsigned short* __restrict__ W2F,
             const unsigned short* __restrict__ W3F,
             const float* __restrict__ B, const float* __restrict__ OB,
             const float* __restrict__ BIASA, float* __restrict__ OUT) {
  __shared__ alignas(16) char LDS[39424];
  const int tid = threadIdx.x;
  const int bm = blockIdx.x;               // 0..2047
  const int n = bm >> 6;
  const int wb = bm & 63;
  const int p0 = wb * 49;
  const int lane = tid & 63, wid = tid >> 6;
  const int li = lane & 15, hi = lane >> 4;
  const int rw = (wid >> 1) << 5;   // 0 or 32
  const int cw = (wid & 1) << 6;    // 0 or 64
  const int cwj = cw >> 4;          // 0 or 4 (jg base)

  // zero V pad rows 49..55 (read as t>=49 operands; must be finite)
  {
    const int off = tid * 8;
    if (off < 1792) *(double*)(LDS + V_OFF + 12544 + off) = 0.0;
  }

  // qkv bias at the PERMUTED logical cols cw + li*4 + j
  float bias[3][4];
#pragma unroll
  for (int s = 0; s < 3; ++s)
#pragma unroll
    for (int j = 0; j < 4; ++j)
      bias[s][j] = B[(cw + li * 4 + j) * 3 + s] * ((s == 0) ? QSCALE : 1.0f);

  // A-fragments DIRECT from global (R12 pattern; rows >=49 compute garbage
  // that every epilogue guard discards)
  s16x8 af[4][2];   // [kc][i]
#pragma unroll
  for (int i = 0; i < 2; ++i) {
    int p = p0 + rw + i * 16 + li;
    if (p > 3135) p = 3135;                    // clamp
    const int r_ = p / 56, c_ = p - r_ * 56;
    int ro = r_ + 4; if (ro >= 56) ro -= 56;   // roll(-4)
    int co = c_ + 4; if (co >= 56) co -= 56;
    const float* src = X + (((size_t)n * 3136 + ro * 56 + co) << 7) + hi * 8;
#pragma unroll
    for (int kc = 0; kc < 4; ++kc) {
      const f32x4 v0 = *(const f32x4*)(src + kc * 32);
      const f32x4 v1 = *(const f32x4*)(src + kc * 32 + 4);
      s16x8 h;
      h[0] = (short)nf2bf(v0.x); h[1] = (short)nf2bf(v0.y);
      h[2] = (short)nf2bf(v0.z); h[3] = (short)nf2bf(v0.w);
      h[4] = (short)nf2bf(v1.x); h[5] = (short)nf2bf(v1.y);
      h[6] = (short)nf2bf(v1.z); h[7] = (short)nf2bf(v1.w);
      af[kc][i] = h;
    }
  }

#define FUSED_PASS(DST, S)                                                      \
  {                                                                             \
    s16x8 bfr[4][4];                                                            \
    _Pragma("unroll")                                                           \
    for (int kc = 0; kc < 4; ++kc)                                              \
      _Pragma("unroll")                                                         \
      for (int j = 0; j < 4; ++j)                                               \
        bfr[kc][j] = *(const s16x8*)(W2F +                                      \
            ((((S) * 4 + kc) * 8 + cwj + j) * 64 + lane) * 8);                  \
    f32x4 acc[2][4];                                                            \
    _Pragma("unroll")                                                           \
    for (int i = 0; i < 2; ++i)                                                 \
      _Pragma("unroll")                                                         \
      for (int j = 0; j < 4; ++j) acc[i][j] = (f32x4){0.f, 0.f, 0.f, 0.f};      \
    __builtin_amdgcn_s_setprio(1);                                              \
    _Pragma("unroll")                                                           \
    for (int kc = 0; kc < 4; ++kc)                                              \
      _Pragma("unroll")                                                         \
      for (int i = 0; i < 2; ++i)                                               \
        _Pragma("unroll")                                                       \
        for (int j = 0; j < 4; ++j)                                             \
          acc[i][j] = MFMA16(af[kc][i], bfr[kc][j], acc[i][j]);                 \
    __builtin_amdgcn_s_setprio(0);                                              \
    _Pragma("unroll")                                                           \
    for (int i = 0; i < 2; ++i)                                                 \
      _Pragma("unroll")                                                         \
      for (int r = 0; r < 4; ++r) {                                             \
        const int row = rw + i * 16 + hi * 4 + r;                               \
        if (row < 49) {                                                         \
          s16x4 h;                                                              \
          _Pragma("unroll")                                                     \
          for (int j = 0; j < 4; ++j)                                           \
            h[j] = (short)nf2bf(acc[i][j][r] + bias[S][j]);                     \
          *(s16x4*)(LDS + (DST) + row * 256 +                                   \
                    ((cw * 2 + li * 8) ^ ((row & 7) << 4))) = h;                \
        }                                                                       \
      }                                                                         \
  }

  FUSED_PASS(Q_OFF, 0)
  FUSED_PASS(K_OFF, 1)
  FUSED_PASS(V_OFF, 2)
#undef FUSED_PASS

  __syncthreads();                  // barrier 1: Q/K/V (+ zeroed V pad) visible

  // ------------------------- attention (per wave) -------------------------
  const int g = wb * 4 + wid;              // window index within n, 0..255
  const int wh = (g >> 3) & 7;
  const int ww = g & 7;
  const int cl = (wh == 7 ? 2 : 0) + (ww == 7 ? 1 : 0);
  const f32x4* bptr = (const f32x4*)(BIASA + (size_t)cl * 4096) + lane;
  char* Pw = LDS + wid * PW_STR;           // per-wave P in dead Q+K (after bar 2)
  const int uw = wid * 49;                 // wave's base u within block tile

  // Q fragments (A-operand) / K fragments (B-operand, PERMUTED k=li*4+t)
  s16x8 qf[4], kf[4];
#pragma unroll
  for (int i = 0; i < 4; ++i) {
    const int uq = uw + i * 16 + li;
    const int pq = uq >> 2, cgq = uq & 3;
    qf[i] = *(const s16x8*)(LDS + Q_OFF + pq * 256 + ((cgq * 64 + hi * 16) ^ ((pq & 7) << 4)));
    const int uk = uw + li * 4 + i;
    const int pk = uk >> 2, cgk = uk & 3;
    kf[i] = *(const s16x8*)(LDS + K_OFF + pk * 256 + ((cgk * 64 + hi * 16) ^ ((pk & 7) << 4)));
  }

  f32x4 sc[4][4];
#pragma unroll
  for (int i = 0; i < 4; ++i)
#pragma unroll
    for (int j = 0; j < 4; ++j) sc[i][j] = bptr[(i * 4 + j) * 64];
  __builtin_amdgcn_s_setprio(1);
#pragma unroll
  for (int i = 0; i < 4; ++i)
#pragma unroll
    for (int j = 0; j < 4; ++j)
      sc[i][j] = MFMA16(qf[i], kf[j], sc[i][j]);   // logits incl. bias+mask
  __builtin_amdgcn_s_setprio(0);

  __syncthreads();                  // barrier 2: Q/K reads done; region -> P

  // softmax numerators -> P (packed b64 writes, natural [q][k] layout)
#pragma unroll
  for (int i = 0; i < 4; ++i) {
#pragma unroll
    for (int r = 0; r < 4; ++r) {
      const int q = i * 16 + hi * 4 + r;
      if (q < 49) {
        s16x4 pb;
#pragma unroll
        for (int j = 0; j < 4; ++j)
          pb[j] = (short)nf2bf(__expf(sc[i][j][r]));
        *(s16x4*)(Pw + q * 128 + ((li * 8) ^ ((q & 7) << 4))) = pb;
      }
    }
  }

  // HOISTED: out-GEMM W3F fragments + OB bias (hide L2 latency under PV)
  s16x8 bfr3[4][4];
#pragma unroll
  for (int kc = 0; kc < 4; ++kc)
#pragma unroll
    for (int j = 0; j < 4; ++j)
      bfr3[kc][j] = *(const s16x8*)(W3F + ((kc * 8 + cwj + j) * 64 + lane) * 8);
  float bias4o[4];
#pragma unroll
  for (int j = 0; j < 4; ++j) bias4o[j] = OB[cw + li * 4 + j];

  // V^T fragments: tile fn col li <-> d = li*2 + fn (conflict-free gather)
  s16x8 vf[2][2];
#pragma unroll
  for (int kc = 0; kc < 2; ++kc)
#pragma unroll
    for (int fn = 0; fn < 2; ++fn) {
      s16x8 tv;
#pragma unroll
      for (int jj = 0; jj < 8; ++jj) {
        const int u = uw + kc * 32 + hi * 8 + jj;
        const int p = u >> 2, cg = u & 3;
        tv[jj] = *(const short*)(LDS + V_OFF + p * 256 + ((cg * 64 + li * 4 + fn * 2) ^ ((p & 7) << 4)));
      }
      vf[kc][fn] = tv;
    }

  s16x8 ones;
#pragma unroll
  for (int e = 0; e < 8; ++e) ones[e] = (short)0x3F80;   // bf16 1.0

  const f32x4 zf = (f32x4){0.f, 0.f, 0.f, 0.f};
  f32x4 o[4][2], osum[4];
#pragma unroll
  for (int i = 0; i < 4; ++i) { o[i][0] = zf; o[i][1] = zf; osum[i] = zf; }
  __builtin_amdgcn_s_setprio(1);
#pragma unroll
  for (int i = 0; i < 4; ++i) {
    const int row = i * 16 + li;
#pragma unroll
    for (int kc = 0; kc < 2; ++kc) {
      const s16x8 pf = *(const s16x8*)(Pw + row * 128 + ((kc * 64 + hi * 16) ^ ((row & 7) << 4)));
      o[i][0] = MFMA16(pf, vf[kc][0], o[i][0]);
      o[i][1] = MFMA16(pf, vf[kc][1], o[i][1]);
      osum[i] = MFMA16(pf, ones, osum[i]);       // row sums, every lane
    }
  }
  __builtin_amdgcn_s_setprio(0);

  __syncthreads();                  // barrier 3: all P reads done; region -> O

  // ---- O -> LDS @0 as [49 rows][128 ch] tile -----------------------------
  // u = g*49 + q  ->  lrow = (49*wid+q)>>2, m = (49*wid+q)&3, ch = m*32+li*2
#pragma unroll
  for (int i = 0; i < 4; ++i)
#pragma unroll
    for (int r = 0; r < 4; ++r) {
      const int q = i * 16 + hi * 4 + r;
      if (q < 49) {
        const float ri = 1.0f / osum[i][r];
        const int ul = 49 * wid + q;
        const int lrow = ul >> 2, m = ul & 3;
        *(unsigned*)(LDS + lrow * 256 +
                     ((m * 64 + li * 4) ^ ((lrow & 7) << 4))) =
            pk2(o[i][0][r] * ri, o[i][1][r] * ri);
      }
    }

  __syncthreads();                  // barrier 4: O tile complete

  // ---- in-block out-GEMM: OUT = O @ out_w.T + out_b, rolled(+3) scatter --
  {
    s16x8 af2[4][2];
#pragma unroll
    for (int kc = 0; kc < 4; ++kc)
#pragma unroll
      for (int i = 0; i < 2; ++i) {
        int ra = rw + i * 16 + li;
        if (ra > 48) ra = 48;
        af2[kc][i] = *(const s16x8*)(LDS + ra * 256 +
                                     ((kc * 64 + hi * 16) ^ ((ra & 7) << 4)));
      }
    f32x4 acc[2][4];
#pragma unroll
    for (int i = 0; i < 2; ++i)
#pragma unroll
      for (int j = 0; j < 4; ++j) acc[i][j] = zf;
    __builtin_amdgcn_s_setprio(1);
#pragma unroll
    for (int kc = 0; kc < 4; ++kc)
#pragma unroll
      for (int i = 0; i < 2; ++i)
#pragma unroll
        for (int j = 0; j < 4; ++j)
          acc[i][j] = MFMA16(af2[kc][i], bfr3[kc][j], acc[i][j]);
    __builtin_amdgcn_s_setprio(0);

#pragma unroll
    for (int i = 0; i < 2; ++i)
#pragma unroll
      for (int r = 0; r < 4; ++r) {
        const int row = rw + i * 16 + hi * 4 + r;
        if (row < 49) {
          const int p = p0 + row;
          const int rs = p / 56, cs = p - rs * 56;
          int rf = rs + 3; if (rf >= 56) rf -= 56;     // roll(+3)
          int cf = cs + 3; if (cf >= 56) cf -= 56;
          f32x4 v;
#pragma unroll
          for (int j = 0; j < 4; ++j) v[j] = acc[i][j][r] + bias4o[j];
          *(f32x4*)(OUT + ((size_t)n * 3136 + rf * 56 + cf) * 128 + cw + li * 4) = v;
        }
      }
  }
}

extern "C" void kernel_launch(void* const* d_in, const int* in_sizes, int n_in,
                              void* d_out, int out_size, void* d_ws, size_t ws_size,
                              hipStream_t stream) {
  const float* x = (const float*)d_in[0];
  const float* qkv_w = (const float*)d_in[1];
  const float* qkv_b = (const float*)d_in[2];
  const float* out_w = (const float*)d_in[3];
  const float* out_b = (const float*)d_in[4];
  const float* rpe = (const float*)d_in[5];
  float* out = (float*)d_out;

  unsigned short* W2F = (unsigned short*)d_ws;             // 49152 bf16 (frag order)
  unsigned short* W3F = W2F + 49152;                       // 16384 bf16 (frag order)
  float* BIASA = (float*)(W3F + 16384);                    // 4*4096 f32

  k_prep<<<36, 256, 0, stream>>>(qkv_w, out_w, rpe, W2F, W3F, BIASA);
  k_fused<<<2048, 256, 0, stream>>>(x, W2F, W3F, qkv_b, out_b, BIASA, out);
}

// Round 22
// 59.129 us; speedup vs baseline: 1.8334x; 1.8334x over previous
//
#include <hip/hip_runtime.h>
#include <hip/hip_bf16.h>

typedef __attribute__((ext_vector_type(4))) float f32x4;
typedef __attribute__((ext_vector_type(8))) short s16x8;
typedef __attribute__((ext_vector_type(4))) short s16x4;

#define MFMA16(a, b, c) __builtin_amdgcn_mfma_f32_16x16x32_bf16(a, b, c, 0, 0, 0)

#define QSCALE 0.17677669529663687f

// integer RNE -- k_prep only
__device__ __forceinline__ unsigned short f2bf(float f) {
  union { float f; unsigned u; } v; v.f = f;
  unsigned u = v.u;
  u += 0x7fff + ((u >> 16) & 1);   // RNE
  return (unsigned short)(u >> 16);
}
// compiler-native RNE conversion (hot path)
__device__ __forceinline__ unsigned short nf2bf(float f) {
  __hip_bfloat16 h = __float2bfloat16(f);
  return *reinterpret_cast<unsigned short*>(&h);
}
__device__ __forceinline__ unsigned pk2(float a, float b) {
  union { unsigned u; unsigned short s[2]; } t;
  t.s[0] = nf2bf(a);
  t.s[1] = nf2bf(b);
  return t.u;
}

// ---------------------------------------------------------------------------
// Prepass.  W2F and W3F in FRAGMENT ORDER (per-(kc,jg) 64-lane x 16B blocks,
// lane l -> logical col c2=((jg>>2)<<6)+li*4+(jg&3), k=kc*32+hi*8); Q-part of
// W2F pre-scaled by QSCALE.  BIASA in MFMA-C layout with permuted k.
// ---------------------------------------------------------------------------
__global__ void k_prep(const float* __restrict__ QW, const float* __restrict__ OW,
                       const float* __restrict__ RPE,
                       unsigned short* __restrict__ W2F, unsigned short* __restrict__ W3F,
                       float* __restrict__ BIASA) {
  const int b = blockIdx.x, t = threadIdx.x;
  if (b < 24) {                       // qkv_w -> fragment order
    const int e = (b * 256 + t) * 8;
    const int bi = e >> 9;            // (s*4+kc)*8 + jg
    const int l = (e >> 3) & 63;
    const int s = bi >> 5;
    const int kc = (bi >> 3) & 3;
    const int jg = bi & 7;
    const int li = l & 15, hi = l >> 4;
    const int c2 = ((jg >> 2) << 6) + li * 4 + (jg & 3);
    const int k0 = kc * 32 + hi * 8;
    const float sf = (s == 0) ? QSCALE : 1.0f;
    const float* src = QW + (size_t)(c2 * 3 + s) * 128 + k0;
#pragma unroll
    for (int q = 0; q < 8; ++q) W2F[e + q] = f2bf(src[q] * sf);
  } else if (b < 32) {                // out_w -> fragment order (W3F)
    const int e = ((b - 24) * 256 + t) * 8;
    const int bi = e >> 9;            // kc*8 + jg
    const int l = (e >> 3) & 63;
    const int kc = bi >> 3;
    const int jg = bi & 7;
    const int li = l & 15, hi = l >> 4;
    const int c2 = ((jg >> 2) << 6) + li * 4 + (jg & 3);
    const int k0 = kc * 32 + hi * 8;
    const float* src = OW + (size_t)c2 * 128 + k0;
#pragma unroll
    for (int q = 0; q < 8; ++q) W3F[e + q] = f2bf(src[q]);
  } else {                            // bias tables in acc-fragment layout
    const int cl = b - 32;
    const int rm = cl >> 1, cm = cl & 1;
    for (int w = 0; w < 16; ++w) {
      const int idx = w * 256 + t;       // ((i*4+j)*64 + lane)*4 + rr
      const int rr = idx & 3;
      const int lane = (idx >> 2) & 63;
      const int ij = idx >> 8;
      const int q = (ij >> 2) * 16 + ((lane >> 4) & 3) * 4 + rr;
      const int k = (lane & 15) * 4 + (ij & 3);       // permuted-k mapping
      float v;
      if (q >= 49 || k >= 49) v = -1.0e30f;
      else {
        const int xq = q / 7, yq = q - xq * 7;
        const int xk = k / 7, yk = k - xk * 7;
        v = RPE[(xk - xq + 6) * 13 + (yk - yq + 6)];
        if (rm && ((xq >= 4) != (xk >= 4))) v = -1.0e30f;
        if (cm && (((yq == 4) && (yk < 4)) || ((yq < 4) && (yk >= 4)))) v = -1.0e30f;
      }
      BIASA[cl * 4096 + idx] = v;
    }
  }
}

// ---------------------------------------------------------------------------
// FULLY FUSED: qkv-GEMM + windowed attention + out-GEMM in ONE kernel
// (R20 configuration = measured best, 59.1us).  Out-GEMM W3F/OB loads hoisted
// above PV; 3 blocks/CU (4-block variant spills, R21).
// LDS: A/O @0 (12544), Q @12544, K @25088, V @37632 (56 rows) = 51968 B.
// ---------------------------------------------------------------------------
#define A_OFF 0
#define Q_OFF 12544
#define K_OFF 25088
#define V_OFF 37632
#define PW_STR 6272

__global__ __launch_bounds__(256, 3)
void k_fused(const float* __restrict__ X, const unsigned short* __restrict__ W2F,
             const unsigned short* __restrict__ W3F,
             const float* __restrict__ B, const float* __restrict__ OB,
             const float* __restrict__ BIASA, float* __restrict__ OUT) {
  __shared__ alignas(16) char LDS[51968];
  const int tid = threadIdx.x;
  const int bm = blockIdx.x;               // 0..2047
  const int n = bm >> 6;
  const int wb = bm & 63;
  const int p0 = wb * 49;
  const int lane = tid & 63, wid = tid >> 6;
  const int li = lane & 15, hi = lane >> 4;
  const int rw = (wid >> 1) << 5;   // 0 or 32
  const int cw = (wid & 1) << 6;    // 0 or 64
  const int cwj = cw >> 4;          // 0 or 4 (jg base)

  // ---- A staging: coalesced (2 rows = 1KB dense per wave-instruction) ----
  {
    const int c16 = lane & 31;      // 16B chunk within 512B row
    const int rh = lane >> 5;       // 0/1: which of the 2 rows
#pragma unroll
    for (int i = 0; i < 7; ++i) {
      const int row = wid * 14 + i * 2 + rh;
      if (row < 49) {
        const int p = p0 + row;
        const int r_ = p / 56, c_ = p - r_ * 56;
        int ro = r_ + 4; if (ro >= 56) ro -= 56;   // roll(-4)
        int co = c_ + 4; if (co >= 56) co -= 56;
        const f32x4 v = *(const f32x4*)(X + (((size_t)n * 3136 + ro * 56 + co) << 7) + c16 * 4);
        s16x4 h;
        h[0] = (short)nf2bf(v.x); h[1] = (short)nf2bf(v.y);
        h[2] = (short)nf2bf(v.z); h[3] = (short)nf2bf(v.w);
        *(s16x4*)(LDS + A_OFF + row * 256 + ((c16 * 8) ^ ((row & 7) << 4))) = h;
      }
    }
  }

  // zero V pad rows 49..55 (read as t>=49 operands; must be finite)
  {
    const int off = tid * 8;
    if (off < 1792) *(double*)(LDS + V_OFF + 12544 + off) = 0.0;
  }

  // qkv bias at the PERMUTED logical cols cw + li*4 + j
  float bias[3][4];
#pragma unroll
  for (int s = 0; s < 3; ++s)
#pragma unroll
    for (int j = 0; j < 4; ++j)
      bias[s][j] = B[(cw + li * 4 + j) * 3 + s] * ((s == 0) ? QSCALE : 1.0f);

  __syncthreads();                  // barrier 1: A tile staged

  // A-fragments from LDS (pad rows clamped; their outputs are discarded)
  s16x8 af[4][2];   // [kc][i]
#pragma unroll
  for (int kc = 0; kc < 4; ++kc)
#pragma unroll
    for (int i = 0; i < 2; ++i) {
      int ra = rw + i * 16 + li;
      if (ra > 48) ra = 48;
      af[kc][i] = *(const s16x8*)(LDS + A_OFF + ra * 256 +
                                  ((kc * 64 + hi * 16) ^ ((ra & 7) << 4)));
    }

#define FUSED_PASS(DST, S)                                                      \
  {                                                                             \
    s16x8 bfr[4][4];                                                            \
    _Pragma("unroll")                                                           \
    for (int kc = 0; kc < 4; ++kc)                                              \
      _Pragma("unroll")                                                         \
      for (int j = 0; j < 4; ++j)                                               \
        bfr[kc][j] = *(const s16x8*)(W2F +                                      \
            ((((S) * 4 + kc) * 8 + cwj + j) * 64 + lane) * 8);                  \
    f32x4 acc[2][4];                                                            \
    _Pragma("unroll")                                                           \
    for (int i = 0; i < 2; ++i)                                                 \
      _Pragma("unroll")                                                         \
      for (int j = 0; j < 4; ++j) acc[i][j] = (f32x4){0.f, 0.f, 0.f, 0.f};      \
    __builtin_amdgcn_s_setprio(1);                                              \
    _Pragma("unroll")                                                           \
    for (int kc = 0; kc < 4; ++kc)                                              \
      _Pragma("unroll")                                                         \
      for (int i = 0; i < 2; ++i)                                               \
        _Pragma("unroll")                                                       \
        for (int j = 0; j < 4; ++j)                                             \
          acc[i][j] = MFMA16(af[kc][i], bfr[kc][j], acc[i][j]);                 \
    __builtin_amdgcn_s_setprio(0);                                              \
    _Pragma("unroll")                                                           \
    for (int i = 0; i < 2; ++i)                                                 \
      _Pragma("unroll")                                                         \
      for (int r = 0; r < 4; ++r) {                                             \
        const int row = rw + i * 16 + hi * 4 + r;                               \
        if (row < 49) {                                                         \
          s16x4 h;                                                              \
          _Pragma("unroll")                                                     \
          for (int j = 0; j < 4; ++j)                                           \
            h[j] = (short)nf2bf(acc[i][j][r] + bias[S][j]);                     \
          *(s16x4*)(LDS + (DST) + row * 256 +                                   \
                    ((cw * 2 + li * 8) ^ ((row & 7) << 4))) = h;                \
        }                                                                       \
      }                                                                         \
  }

  FUSED_PASS(Q_OFF, 0)
  FUSED_PASS(K_OFF, 1)
  FUSED_PASS(V_OFF, 2)
#undef FUSED_PASS

  __syncthreads();                  // barrier 2: Q/K/V (+ zeroed V pad) visible

  // ------------------------- attention (per wave) -------------------------
  const int g = wb * 4 + wid;              // window index within n, 0..255
  const int wh = (g >> 3) & 7;
  const int ww = g & 7;
  const int cl = (wh == 7 ? 2 : 0) + (ww == 7 ? 1 : 0);
  const f32x4* bptr = (const f32x4*)(BIASA + (size_t)cl * 4096) + lane;
  char* Pw = LDS + Q_OFF + wid * PW_STR;   // reuses dead Q/K region (after bar)
  const int uw = wid * 49;                 // wave's base u within block tile

  // Q fragments (A-operand) / K fragments (B-operand, PERMUTED k=li*4+t)
  s16x8 qf[4], kf[4];
#pragma unroll
  for (int i = 0; i < 4; ++i) {
    const int uq = uw + i * 16 + li;
    const int pq = uq >> 2, cgq = uq & 3;
    qf[i] = *(const s16x8*)(LDS + Q_OFF + pq * 256 + ((cgq * 64 + hi * 16) ^ ((pq & 7) << 4)));
    const int uk = uw + li * 4 + i;
    const int pk = uk >> 2, cgk = uk & 3;
    kf[i] = *(const s16x8*)(LDS + K_OFF + pk * 256 + ((cgk * 64 + hi * 16) ^ ((pk & 7) << 4)));
  }

  f32x4 sc[4][4];
#pragma unroll
  for (int i = 0; i < 4; ++i)
#pragma unroll
    for (int j = 0; j < 4; ++j) sc[i][j] = bptr[(i * 4 + j) * 64];
  __builtin_amdgcn_s_setprio(1);
#pragma unroll
  for (int i = 0; i < 4; ++i)
#pragma unroll
    for (int j = 0; j < 4; ++j)
      sc[i][j] = MFMA16(qf[i], kf[j], sc[i][j]);   // logits incl. bias+mask
  __builtin_amdgcn_s_setprio(0);

  __syncthreads();                  // barrier 3: Q/K reads done; region -> P

  // softmax numerators -> P (packed b64 writes, natural [q][k] layout)
#pragma unroll
  for (int i = 0; i < 4; ++i) {
#pragma unroll
    for (int r = 0; r < 4; ++r) {
      const int q = i * 16 + hi * 4 + r;
      if (q < 49) {
        s16x4 pb;
#pragma unroll
        for (int j = 0; j < 4; ++j)
          pb[j] = (short)nf2bf(__expf(sc[i][j][r]));
        *(s16x4*)(Pw + q * 128 + ((li * 8) ^ ((q & 7) << 4))) = pb;
      }
    }
  }

  // HOISTED: out-GEMM W3F fragments + OB bias -- issued here so their L2
  // latency hides under PV MFMAs + O-writes + barrier 4.
  s16x8 bfr3[4][4];
#pragma unroll
  for (int kc = 0; kc < 4; ++kc)
#pragma unroll
    for (int j = 0; j < 4; ++j)
      bfr3[kc][j] = *(const s16x8*)(W3F + ((kc * 8 + cwj + j) * 64 + lane) * 8);
  float bias4o[4];
#pragma unroll
  for (int j = 0; j < 4; ++j) bias4o[j] = OB[cw + li * 4 + j];

  // V^T fragments: tile fn col li <-> d = li*2 + fn (conflict-free gather)
  s16x8 vf[2][2];
#pragma unroll
  for (int kc = 0; kc < 2; ++kc)
#pragma unroll
    for (int fn = 0; fn < 2; ++fn) {
      s16x8 tv;
#pragma unroll
      for (int jj = 0; jj < 8; ++jj) {
        const int u = uw + kc * 32 + hi * 8 + jj;
        const int p = u >> 2, cg = u & 3;
        tv[jj] = *(const short*)(LDS + V_OFF + p * 256 + ((cg * 64 + li * 4 + fn * 2) ^ ((p & 7) << 4)));
      }
      vf[kc][fn] = tv;
    }

  s16x8 ones;
#pragma unroll
  for (int e = 0; e < 8; ++e) ones[e] = (short)0x3F80;   // bf16 1.0

  const f32x4 zf = (f32x4){0.f, 0.f, 0.f, 0.f};
  f32x4 o[4][2], osum[4];
#pragma unroll
  for (int i = 0; i < 4; ++i) { o[i][0] = zf; o[i][1] = zf; osum[i] = zf; }
  __builtin_amdgcn_s_setprio(1);
#pragma unroll
  for (int i = 0; i < 4; ++i) {
    const int row = i * 16 + li;
#pragma unroll
    for (int kc = 0; kc < 2; ++kc) {
      const s16x8 pf = *(const s16x8*)(Pw + row * 128 + ((kc * 64 + hi * 16) ^ ((row & 7) << 4)));
      o[i][0] = MFMA16(pf, vf[kc][0], o[i][0]);
      o[i][1] = MFMA16(pf, vf[kc][1], o[i][1]);
      osum[i] = MFMA16(pf, ones, osum[i]);       // row sums, every lane
    }
  }
  __builtin_amdgcn_s_setprio(0);

  // ---- O -> LDS A-region as [49 rows][128 ch] tile (A is long dead) ------
  // u = g*49 + q  ->  lrow = (49*wid+q)>>2, m = (49*wid+q)&3, ch = m*32+li*2
#pragma unroll
  for (int i = 0; i < 4; ++i)
#pragma unroll
    for (int r = 0; r < 4; ++r) {
      const int q = i * 16 + hi * 4 + r;
      if (q < 49) {
        const float ri = 1.0f / osum[i][r];
        const int ul = 49 * wid + q;
        const int lrow = ul >> 2, m = ul & 3;
        *(unsigned*)(LDS + A_OFF + lrow * 256 +
                     ((m * 64 + li * 4) ^ ((lrow & 7) << 4))) =
            pk2(o[i][0][r] * ri, o[i][1][r] * ri);
      }
    }

  __syncthreads();                  // barrier 4: O tile complete

  // ---- in-block out-GEMM: OUT = O @ out_w.T + out_b, rolled(+3) scatter --
  {
    s16x8 af2[4][2];
#pragma unroll
    for (int kc = 0; kc < 4; ++kc)
#pragma unroll
      for (int i = 0; i < 2; ++i) {
        int ra = rw + i * 16 + li;
        if (ra > 48) ra = 48;
        af2[kc][i] = *(const s16x8*)(LDS + A_OFF + ra * 256 +
                                     ((kc * 64 + hi * 16) ^ ((ra & 7) << 4)));
      }
    f32x4 acc[2][4];
#pragma unroll
    for (int i = 0; i < 2; ++i)
#pragma unroll
      for (int j = 0; j < 4; ++j) acc[i][j] = zf;
    __builtin_amdgcn_s_setprio(1);
#pragma unroll
    for (int kc = 0; kc < 4; ++kc)
#pragma unroll
      for (int i = 0; i < 2; ++i)
#pragma unroll
        for (int j = 0; j < 4; ++j)
          acc[i][j] = MFMA16(af2[kc][i], bfr3[kc][j], acc[i][j]);
    __builtin_amdgcn_s_setprio(0);

#pragma unroll
    for (int i = 0; i < 2; ++i)
#pragma unroll
      for (int r = 0; r < 4; ++r) {
        const int row = rw + i * 16 + hi * 4 + r;
        if (row < 49) {
          const int p = p0 + row;
          const int rs = p / 56, cs = p - rs * 56;
          int rf = rs + 3; if (rf >= 56) rf -= 56;     // roll(+3)
          int cf = cs + 3; if (cf >= 56) cf -= 56;
          f32x4 v;
#pragma unroll
          for (int j = 0; j < 4; ++j) v[j] = acc[i][j][r] + bias4o[j];
          *(f32x4*)(OUT + ((size_t)n * 3136 + rf * 56 + cf) * 128 + cw + li * 4) = v;
        }
      }
  }
}

extern "C" void kernel_launch(void* const* d_in, const int* in_sizes, int n_in,
                              void* d_out, int out_size, void* d_ws, size_t ws_size,
                              hipStream_t stream) {
  const float* x = (const float*)d_in[0];
  const float* qkv_w = (const float*)d_in[1];
  const float* qkv_b = (const float*)d_in[2];
  const float* out_w = (const float*)d_in[3];
  const float* out_b = (const float*)d_in[4];
  const float* rpe = (const float*)d_in[5];
  float* out = (float*)d_out;

  unsigned short* W2F = (unsigned short*)d_ws;             // 49152 bf16 (frag order)
  unsigned short* W3F = W2F + 49152;                       // 16384 bf16 (frag order)
  float* BIASA = (float*)(W3F + 16384);                    // 4*4096 f32

  k_prep<<<36, 256, 0, stream>>>(qkv_w, out_w, rpe, W2F, W3F, BIASA);
  k_fused<<<2048, 256, 0, stream>>>(x, W2F, W3F, qkv_b, out_b, BIASA, out);
}

// Round 23
// 58.653 us; speedup vs baseline: 1.8483x; 1.0081x over previous
//
#include <hip/hip_runtime.h>
#include <hip/hip_bf16.h>

typedef __attribute__((ext_vector_type(4))) float f32x4;
typedef __attribute__((ext_vector_type(8))) short s16x8;
typedef __attribute__((ext_vector_type(4))) short s16x4;

#define MFMA16(a, b, c) __builtin_amdgcn_mfma_f32_16x16x32_bf16(a, b, c, 0, 0, 0)

#define QSCALE 0.17677669529663687f

// integer RNE -- k_prep only
__device__ __forceinline__ unsigned short f2bf(float f) {
  union { float f; unsigned u; } v; v.f = f;
  unsigned u = v.u;
  u += 0x7fff + ((u >> 16) & 1);   // RNE
  return (unsigned short)(u >> 16);
}
// compiler-native RNE conversion (hot path)
__device__ __forceinline__ unsigned short nf2bf(float f) {
  __hip_bfloat16 h = __float2bfloat16(f);
  return *reinterpret_cast<unsigned short*>(&h);
}
__device__ __forceinline__ unsigned pk2(float a, float b) {
  union { unsigned u; unsigned short s[2]; } t;
  t.s[0] = nf2bf(a);
  t.s[1] = nf2bf(b);
  return t.u;
}

// ---------------------------------------------------------------------------
// Prepass (unchanged).  W2F/W3F fragment order; BIASA MFMA-C layout.
// ---------------------------------------------------------------------------
__global__ void k_prep(const float* __restrict__ QW, const float* __restrict__ OW,
                       const float* __restrict__ RPE,
                       unsigned short* __restrict__ W2F, unsigned short* __restrict__ W3F,
                       float* __restrict__ BIASA) {
  const int b = blockIdx.x, t = threadIdx.x;
  if (b < 24) {                       // qkv_w -> fragment order
    const int e = (b * 256 + t) * 8;
    const int bi = e >> 9;            // (s*4+kc)*8 + jg
    const int l = (e >> 3) & 63;
    const int s = bi >> 5;
    const int kc = (bi >> 3) & 3;
    const int jg = bi & 7;
    const int li = l & 15, hi = l >> 4;
    const int c2 = ((jg >> 2) << 6) + li * 4 + (jg & 3);
    const int k0 = kc * 32 + hi * 8;
    const float sf = (s == 0) ? QSCALE : 1.0f;
    const float* src = QW + (size_t)(c2 * 3 + s) * 128 + k0;
#pragma unroll
    for (int q = 0; q < 8; ++q) W2F[e + q] = f2bf(src[q] * sf);
  } else if (b < 32) {                // out_w -> fragment order (W3F)
    const int e = ((b - 24) * 256 + t) * 8;
    const int bi = e >> 9;            // kc*8 + jg
    const int l = (e >> 3) & 63;
    const int kc = bi >> 3;
    const int jg = bi & 7;
    const int li = l & 15, hi = l >> 4;
    const int c2 = ((jg >> 2) << 6) + li * 4 + (jg & 3);
    const int k0 = kc * 32 + hi * 8;
    const float* src = OW + (size_t)c2 * 128 + k0;
#pragma unroll
    for (int q = 0; q < 8; ++q) W3F[e + q] = f2bf(src[q]);
  } else {                            // bias tables in acc-fragment layout
    const int cl = b - 32;
    const int rm = cl >> 1, cm = cl & 1;
    for (int w = 0; w < 16; ++w) {
      const int idx = w * 256 + t;       // ((i*4+j)*64 + lane)*4 + rr
      const int rr = idx & 3;
      const int lane = (idx >> 2) & 63;
      const int ij = idx >> 8;
      const int q = (ij >> 2) * 16 + ((lane >> 4) & 3) * 4 + rr;
      const int k = (lane & 15) * 4 + (ij & 3);       // permuted-k mapping
      float v;
      if (q >= 49 || k >= 49) v = -1.0e30f;
      else {
        const int xq = q / 7, yq = q - xq * 7;
        const int xk = k / 7, yk = k - xk * 7;
        v = RPE[(xk - xq + 6) * 13 + (yk - yq + 6)];
        if (rm && ((xq >= 4) != (xk >= 4))) v = -1.0e30f;
        if (cm && (((yq == 4) && (yk < 4)) || ((yq < 4) && (yk >= 4)))) v = -1.0e30f;
      }
      BIASA[cl * 4096 + idx] = v;
    }
  }
}

// ---------------------------------------------------------------------------
// FULLY FUSED, 39424 B LDS (R21 structure) with __launch_bounds__(256,3):
// compiler keeps ~84-116 VGPR (NO spill), and the hardware admits 4 blocks/CU
// by LDS capacity (4 x 39424 = 157696 <= 163840).  This is the clean 4-block
// occupancy experiment R21 confounded with a 64-VGPR cap.
// LDS: Q @0 (12544), K @12544, V @25088 (56 rows, 49..55 zeroed) = 39424 B.
// P = per-wave 6272 B at wid*6272 (spans Q+K, after barrier 2).
// O = [49][128ch] tile at 0 (written after barrier 3).
// ---------------------------------------------------------------------------
#define Q_OFF 0
#define K_OFF 12544
#define V_OFF 25088
#define PW_STR 6272

__global__ __launch_bounds__(256, 3)
void k_fused(const float* __restrict__ X, const unsigned short* __restrict__ W2F,
             const unsigned short* __restrict__ W3F,
             const float* __restrict__ B, const float* __restrict__ OB,
             const float* __restrict__ BIASA, float* __restrict__ OUT) {
  __shared__ alignas(16) char LDS[39424];
  const int tid = threadIdx.x;
  const int bm = blockIdx.x;               // 0..2047
  const int n = bm >> 6;
  const int wb = bm & 63;
  const int p0 = wb * 49;
  const int lane = tid & 63, wid = tid >> 6;
  const int li = lane & 15, hi = lane >> 4;
  const int rw = (wid >> 1) << 5;   // 0 or 32
  const int cw = (wid & 1) << 6;    // 0 or 64
  const int cwj = cw >> 4;          // 0 or 4 (jg base)

  // zero V pad rows 49..55 (read as t>=49 operands; must be finite)
  {
    const int off = tid * 8;
    if (off < 1792) *(double*)(LDS + V_OFF + 12544 + off) = 0.0;
  }

  // qkv bias at the PERMUTED logical cols cw + li*4 + j
  float bias[3][4];
#pragma unroll
  for (int s = 0; s < 3; ++s)
#pragma unroll
    for (int j = 0; j < 4; ++j)
      bias[s][j] = B[(cw + li * 4 + j) * 3 + s] * ((s == 0) ? QSCALE : 1.0f);

  // A-fragments DIRECT from global (R12 pattern; rows >=49 compute garbage
  // that every epilogue guard discards)
  s16x8 af[4][2];   // [kc][i]
#pragma unroll
  for (int i = 0; i < 2; ++i) {
    int p = p0 + rw + i * 16 + li;
    if (p > 3135) p = 3135;                    // clamp
    const int r_ = p / 56, c_ = p - r_ * 56;
    int ro = r_ + 4; if (ro >= 56) ro -= 56;   // roll(-4)
    int co = c_ + 4; if (co >= 56) co -= 56;
    const float* src = X + (((size_t)n * 3136 + ro * 56 + co) << 7) + hi * 8;
#pragma unroll
    for (int kc = 0; kc < 4; ++kc) {
      const f32x4 v0 = *(const f32x4*)(src + kc * 32);
      const f32x4 v1 = *(const f32x4*)(src + kc * 32 + 4);
      s16x8 h;
      h[0] = (short)nf2bf(v0.x); h[1] = (short)nf2bf(v0.y);
      h[2] = (short)nf2bf(v0.z); h[3] = (short)nf2bf(v0.w);
      h[4] = (short)nf2bf(v1.x); h[5] = (short)nf2bf(v1.y);
      h[6] = (short)nf2bf(v1.z); h[7] = (short)nf2bf(v1.w);
      af[kc][i] = h;
    }
  }

#define FUSED_PASS(DST, S)                                                      \
  {                                                                             \
    s16x8 bfr[4][4];                                                            \
    _Pragma("unroll")                                                           \
    for (int kc = 0; kc < 4; ++kc)                                              \
      _Pragma("unroll")                                                         \
      for (int j = 0; j < 4; ++j)                                               \
        bfr[kc][j] = *(const s16x8*)(W2F +                                      \
            ((((S) * 4 + kc) * 8 + cwj + j) * 64 + lane) * 8);                  \
    f32x4 acc[2][4];                                                            \
    _Pragma("unroll")                                                           \
    for (int i = 0; i < 2; ++i)                                                 \
      _Pragma("unroll")                                                         \
      for (int j = 0; j < 4; ++j) acc[i][j] = (f32x4){0.f, 0.f, 0.f, 0.f};      \
    __builtin_amdgcn_s_setprio(1);                                              \
    _Pragma("unroll")                                                           \
    for (int kc = 0; kc < 4; ++kc)                                              \
      _Pragma("unroll")                                                         \
      for (int i = 0; i < 2; ++i)                                               \
        _Pragma("unroll")                                                       \
        for (int j = 0; j < 4; ++j)                                             \
          acc[i][j] = MFMA16(af[kc][i], bfr[kc][j], acc[i][j]);                 \
    __builtin_amdgcn_s_setprio(0);                                              \
    _Pragma("unroll")                                                           \
    for (int i = 0; i < 2; ++i)                                                 \
      _Pragma("unroll")                                                         \
      for (int r = 0; r < 4; ++r) {                                             \
        const int row = rw + i * 16 + hi * 4 + r;                               \
        if (row < 49) {                                                         \
          s16x4 h;                                                              \
          _Pragma("unroll")                                                     \
          for (int j = 0; j < 4; ++j)                                           \
            h[j] = (short)nf2bf(acc[i][j][r] + bias[S][j]);                     \
          *(s16x4*)(LDS + (DST) + row * 256 +                                   \
                    ((cw * 2 + li * 8) ^ ((row & 7) << 4))) = h;                \
        }                                                                       \
      }                                                                         \
  }

  FUSED_PASS(Q_OFF, 0)
  FUSED_PASS(K_OFF, 1)
  FUSED_PASS(V_OFF, 2)
#undef FUSED_PASS

  __syncthreads();                  // barrier 1: Q/K/V (+ zeroed V pad) visible

  // ------------------------- attention (per wave) -------------------------
  const int g = wb * 4 + wid;              // window index within n, 0..255
  const int wh = (g >> 3) & 7;
  const int ww = g & 7;
  const int cl = (wh == 7 ? 2 : 0) + (ww == 7 ? 1 : 0);
  const f32x4* bptr = (const f32x4*)(BIASA + (size_t)cl * 4096) + lane;
  char* Pw = LDS + wid * PW_STR;           // per-wave P in dead Q+K (after bar 2)
  const int uw = wid * 49;                 // wave's base u within block tile

  // Q fragments (A-operand) / K fragments (B-operand, PERMUTED k=li*4+t)
  s16x8 qf[4], kf[4];
#pragma unroll
  for (int i = 0; i < 4; ++i) {
    const int uq = uw + i * 16 + li;
    const int pq = uq >> 2, cgq = uq & 3;
    qf[i] = *(const s16x8*)(LDS + Q_OFF + pq * 256 + ((cgq * 64 + hi * 16) ^ ((pq & 7) << 4)));
    const int uk = uw + li * 4 + i;
    const int pk = uk >> 2, cgk = uk & 3;
    kf[i] = *(const s16x8*)(LDS + K_OFF + pk * 256 + ((cgk * 64 + hi * 16) ^ ((pk & 7) << 4)));
  }

  f32x4 sc[4][4];
#pragma unroll
  for (int i = 0; i < 4; ++i)
#pragma unroll
    for (int j = 0; j < 4; ++j) sc[i][j] = bptr[(i * 4 + j) * 64];
  __builtin_amdgcn_s_setprio(1);
#pragma unroll
  for (int i = 0; i < 4; ++i)
#pragma unroll
    for (int j = 0; j < 4; ++j)
      sc[i][j] = MFMA16(qf[i], kf[j], sc[i][j]);   // logits incl. bias+mask
  __builtin_amdgcn_s_setprio(0);

  __syncthreads();                  // barrier 2: Q/K reads done; region -> P

  // softmax numerators -> P (packed b64 writes, natural [q][k] layout)
#pragma unroll
  for (int i = 0; i < 4; ++i) {
#pragma unroll
    for (int r = 0; r < 4; ++r) {
      const int q = i * 16 + hi * 4 + r;
      if (q < 49) {
        s16x4 pb;
#pragma unroll
        for (int j = 0; j < 4; ++j)
          pb[j] = (short)nf2bf(__expf(sc[i][j][r]));
        *(s16x4*)(Pw + q * 128 + ((li * 8) ^ ((q & 7) << 4))) = pb;
      }
    }
  }

  // HOISTED: out-GEMM W3F fragments + OB bias (hide L2 latency under PV)
  s16x8 bfr3[4][4];
#pragma unroll
  for (int kc = 0; kc < 4; ++kc)
#pragma unroll
    for (int j = 0; j < 4; ++j)
      bfr3[kc][j] = *(const s16x8*)(W3F + ((kc * 8 + cwj + j) * 64 + lane) * 8);
  float bias4o[4];
#pragma unroll
  for (int j = 0; j < 4; ++j) bias4o[j] = OB[cw + li * 4 + j];

  // V^T fragments: tile fn col li <-> d = li*2 + fn (conflict-free gather)
  s16x8 vf[2][2];
#pragma unroll
  for (int kc = 0; kc < 2; ++kc)
#pragma unroll
    for (int fn = 0; fn < 2; ++fn) {
      s16x8 tv;
#pragma unroll
      for (int jj = 0; jj < 8; ++jj) {
        const int u = uw + kc * 32 + hi * 8 + jj;
        const int p = u >> 2, cg = u & 3;
        tv[jj] = *(const short*)(LDS + V_OFF + p * 256 + ((cg * 64 + li * 4 + fn * 2) ^ ((p & 7) << 4)));
      }
      vf[kc][fn] = tv;
    }

  s16x8 ones;
#pragma unroll
  for (int e = 0; e < 8; ++e) ones[e] = (short)0x3F80;   // bf16 1.0

  const f32x4 zf = (f32x4){0.f, 0.f, 0.f, 0.f};
  f32x4 o[4][2], osum[4];
#pragma unroll
  for (int i = 0; i < 4; ++i) { o[i][0] = zf; o[i][1] = zf; osum[i] = zf; }
  __builtin_amdgcn_s_setprio(1);
#pragma unroll
  for (int i = 0; i < 4; ++i) {
    const int row = i * 16 + li;
#pragma unroll
    for (int kc = 0; kc < 2; ++kc) {
      const s16x8 pf = *(const s16x8*)(Pw + row * 128 + ((kc * 64 + hi * 16) ^ ((row & 7) << 4)));
      o[i][0] = MFMA16(pf, vf[kc][0], o[i][0]);
      o[i][1] = MFMA16(pf, vf[kc][1], o[i][1]);
      osum[i] = MFMA16(pf, ones, osum[i]);       // row sums, every lane
    }
  }
  __builtin_amdgcn_s_setprio(0);

  __syncthreads();                  // barrier 3: all P reads done; region -> O

  // ---- O -> LDS @0 as [49 rows][128 ch] tile -----------------------------
  // u = g*49 + q  ->  lrow = (49*wid+q)>>2, m = (49*wid+q)&3, ch = m*32+li*2
#pragma unroll
  for (int i = 0; i < 4; ++i)
#pragma unroll
    for (int r = 0; r < 4; ++r) {
      const int q = i * 16 + hi * 4 + r;
      if (q < 49) {
        const float ri = 1.0f / osum[i][r];
        const int ul = 49 * wid + q;
        const int lrow = ul >> 2, m = ul & 3;
        *(unsigned*)(LDS + lrow * 256 +
                     ((m * 64 + li * 4) ^ ((lrow & 7) << 4))) =
            pk2(o[i][0][r] * ri, o[i][1][r] * ri);
      }
    }

  __syncthreads();                  // barrier 4: O tile complete

  // ---- in-block out-GEMM: OUT = O @ out_w.T + out_b, rolled(+3) scatter --
  {
    s16x8 af2[4][2];
#pragma unroll
    for (int kc = 0; kc < 4; ++kc)
#pragma unroll
      for (int i = 0; i < 2; ++i) {
        int ra = rw + i * 16 + li;
        if (ra > 48) ra = 48;
        af2[kc][i] = *(const s16x8*)(LDS + ra * 256 +
                                     ((kc * 64 + hi * 16) ^ ((ra & 7) << 4)));
      }
    f32x4 acc[2][4];
#pragma unroll
    for (int i = 0; i < 2; ++i)
#pragma unroll
      for (int j = 0; j < 4; ++j) acc[i][j] = zf;
    __builtin_amdgcn_s_setprio(1);
#pragma unroll
    for (int kc = 0; kc < 4; ++kc)
#pragma unroll
      for (int i = 0; i < 2; ++i)
#pragma unroll
        for (int j = 0; j < 4; ++j)
          acc[i][j] = MFMA16(af2[kc][i], bfr3[kc][j], acc[i][j]);
    __builtin_amdgcn_s_setprio(0);

#pragma unroll
    for (int i = 0; i < 2; ++i)
#pragma unroll
      for (int r = 0; r < 4; ++r) {
        const int row = rw + i * 16 + hi * 4 + r;
        if (row < 49) {
          const int p = p0 + row;
          const int rs = p / 56, cs = p - rs * 56;
          int rf = rs + 3; if (rf >= 56) rf -= 56;     // roll(+3)
          int cf = cs + 3; if (cf >= 56) cf -= 56;
          f32x4 v;
#pragma unroll
          for (int j = 0; j < 4; ++j) v[j] = acc[i][j][r] + bias4o[j];
          *(f32x4*)(OUT + ((size_t)n * 3136 + rf * 56 + cf) * 128 + cw + li * 4) = v;
        }
      }
  }
}

extern "C" void kernel_launch(void* const* d_in, const int* in_sizes, int n_in,
                              void* d_out, int out_size, void* d_ws, size_t ws_size,
                              hipStream_t stream) {
  const float* x = (const float*)d_in[0];
  const float* qkv_w = (const float*)d_in[1];
  const float* qkv_b = (const float*)d_in[2];
  const float* out_w = (const float*)d_in[3];
  const float* out_b = (const float*)d_in[4];
  const float* rpe = (const float*)d_in[5];
  float* out = (float*)d_out;

  unsigned short* W2F = (unsigned short*)d_ws;             // 49152 bf16 (frag order)
  unsigned short* W3F = W2F + 49152;                       // 16384 bf16 (frag order)
  float* BIASA = (float*)(W3F + 16384);                    // 4*4096 f32

  k_prep<<<36, 256, 0, stream>>>(qkv_w, out_w, rpe, W2F, W3F, BIASA);
  k_fused<<<2048, 256, 0, stream>>>(x, W2F, W3F, qkv_b, out_b, BIASA, out);
}